// Round 13
// baseline (152.836 us; speedup 1.0000x reference)
//
#include <hip/hip_runtime.h>
#include <hip/hip_bf16.h>
#include <hip/hip_fp16.h>

// GAT 2-layer forward for MI355X — round 13.
// Changes vs round 12:
//  - gemm W-staging K-SPLIT (two 64-wide phases): LDS 34->18.4 KB so mega hits
//    the 8-blocks/CU thread cap (one scheduling wave for gemm+bin); gemm2 9.2KB.
//  - as2/ad2 computed in node1's epilogue via precomputed v_s2=W2@att_s2,
//    v_d2=W2@att_d2 (one extra mega block); gemm2 epilogue deleted (DO_ATT=0).
//  - node gather loops unchanged (at their measured random-gather ceiling).

#define SLOPE 0.2f
static __device__ __forceinline__ float lrelu(float a) { return a > 0.f ? a : SLOPE * a; }

#define NBK_MAX 256  // max buckets (N <= 65536)

typedef _Float16 half8 __attribute__((ext_vector_type(8)));
typedef float f32x4 __attribute__((ext_vector_type(4)));

// ---------------- MEGA: MFMA GEMM (+ fused bin, + fused v2-precompute) ----------------

// W fp32 [K][NOUT] row-major, staged K-half at a time into LDS as W^T fp16.
// FUSE_BIN: blocks [gemmBlocks, gridDim-1) bin edges into bucket slabs;
//           block gridDim-1 computes v_s2/v_d2 = W2 @ att_{s,d}2.
template <int K, int NOUT, int H, bool FUSE_BIN, bool DO_ATT, int CHUNK, typename AT>
__global__ __launch_bounds__(256) void gemm_bin_mfma(
    const AT* __restrict__ A, const float* __restrict__ Wg,
    const float* __restrict__ att_s, const float* __restrict__ att_d,
    __half* __restrict__ Y, float* __restrict__ AS, float* __restrict__ AD,
    int M, int gemmBlocks,
    const int* __restrict__ srcArr, const int* __restrict__ dstArr,
    int* __restrict__ cursor, unsigned int* __restrict__ binned,
    int E2, int nbk, int capb,
    const float* __restrict__ W2g, const float* __restrict__ as2wg,
    const float* __restrict__ ad2wg, float* __restrict__ vs2, float* __restrict__ vd2) {
  constexpr int NT = NOUT / 16;
  constexpr int NTH = NT / H;
  constexpr int KH = 64;           // K-half
  constexpr int LDW = KH + 8;      // padded staged row (halfs)
  constexpr int LDY = NOUT + 8;
  constexpr int WTS_B = NOUT * LDW * 2;
  constexpr int YLDS_B = 4 * 16 * LDY * 2;
  constexpr int GEMM_B = (WTS_B > YLDS_B) ? WTS_B : YLDS_B;  // ylds aliases wts
  constexpr int BIN_B = 5 * 256 * 4 + CHUNK * 4;
  constexpr int SMEM_B = (FUSE_BIN && BIN_B > GEMM_B) ? BIN_B : GEMM_B;
  __shared__ __align__(16) char smem[SMEM_B];

  int tid = threadIdx.x;

  if constexpr (FUSE_BIN) {
    if ((int)blockIdx.x == (int)gridDim.x - 1) {
      // ---- v2 precompute branch: vs2[c] = sum_j W2[c][j]*att_s2[j] ----
      for (int c = tid; c < 128; c += 256) {
        float s = 0.f, d = 0.f;
        for (int j = 0; j < 64; j++) {
          float w = W2g[c * 64 + j];
          s = fmaf(w, as2wg[j], s);
          d = fmaf(w, ad2wg[j], d);
        }
        vs2[c] = s;
        vd2[c] = d;
      }
      return;
    }
    if ((int)blockIdx.x >= gemmBlocks) {
      // ---- bin branch ----
      int* hist = (int*)smem;
      int* lbase = hist + 256;
      int* lcur = lbase + 256;
      int* gpos = lcur + 256;
      int* sh = gpos + 256;
      unsigned int* stage = (unsigned int*)(sh + 256);
      constexpr int PT = CHUNK / 256;
      int t = tid;
      int bb = blockIdx.x - gemmBlocks;
      int e0 = bb * CHUNK;
      int cnt = min(CHUNK, E2 - e0);

      hist[t] = 0;
      __syncthreads();

      unsigned int pk[PT];
#pragma unroll
      for (int i = 0; i < PT; i++) {
        int e = e0 + t + i * 256;
        if (e < E2) {
          int s = srcArr[e], d = dstArr[e];
          int b = d >> 8;
          pk[i] = ((unsigned)b << 24) | ((unsigned)s << 8) | (unsigned)(d & 255);
          atomicAdd(&hist[b], 1);
        } else {
          pk[i] = 0xFFFFFFFFu;
        }
      }
      __syncthreads();

      int hv = hist[t];
      sh[t] = hv;
      __syncthreads();
      for (int o = 1; o < 256; o <<= 1) {
        int u = (t >= o) ? sh[t - o] : 0;
        __syncthreads();
        sh[t] += u;
        __syncthreads();
      }
      lbase[t] = sh[t] - hv;
      lcur[t] = sh[t] - hv;
      gpos[t] = hv ? (t * capb + atomicAdd(&cursor[t], hv)) : 0;
      __syncthreads();

#pragma unroll
      for (int i = 0; i < PT; i++) {
        if (pk[i] != 0xFFFFFFFFu) {
          int b = pk[i] >> 24;
          int lp = atomicAdd(&lcur[b], 1);
          stage[lp] = pk[i];
        }
      }
      __syncthreads();

      for (int i = t; i < cnt; i += 256) {
        unsigned int v = stage[i];
        int b = v >> 24;
        binned[gpos[b] + (i - lbase[b])] = v;
      }
      return;
    }
  }

  // ---- gemm branch ----
  __half* wts = (__half*)smem;
  __half(*ylds)[16 * LDY] = (__half(*)[16 * LDY])smem;  // aliases wts (time-disjoint)

  int w = tid >> 6;
  int lane = tid & 63;
  int lrow = lane & 15;
  int lch = lane >> 4;
  int r0w = blockIdx.x * 64 + w * 16;
  bool active = (r0w < M);

  f32x4 acc[NT];
#pragma unroll
  for (int nt = 0; nt < NT; nt++) acc[nt] = (f32x4){0.f, 0.f, 0.f, 0.f};

  half8 afrag[K / 32];
  if (active) {
    if constexpr (sizeof(AT) == 4) {
      const float* arow = (const float*)A + (size_t)(r0w + lrow) * K + lch * 8;
#pragma unroll
      for (int kk = 0; kk < K / 32; kk++) {
        float4 v0 = *(const float4*)(arow + kk * 32);
        float4 v1 = *(const float4*)(arow + kk * 32 + 4);
        half8 a;
        a[0] = (_Float16)v0.x; a[1] = (_Float16)v0.y;
        a[2] = (_Float16)v0.z; a[3] = (_Float16)v0.w;
        a[4] = (_Float16)v1.x; a[5] = (_Float16)v1.y;
        a[6] = (_Float16)v1.z; a[7] = (_Float16)v1.w;
        afrag[kk] = a;
      }
    } else {
      const __half* arow = (const __half*)A + (size_t)(r0w + lrow) * K + lch * 8;
#pragma unroll
      for (int kk = 0; kk < K / 32; kk++) afrag[kk] = *(const half8*)(arow + kk * 32);
    }
  }

  // two K-half phases: stage W^T half, run its MFMAs
#pragma unroll
  for (int ph = 0; ph < 2; ph++) {
    for (int idx = tid; idx < NOUT * KH; idx += 256) {
      int kl = idx / NOUT, c = idx - kl * NOUT;
      wts[c * LDW + kl] = __float2half(Wg[(ph * KH + kl) * NOUT + c]);
    }
    __syncthreads();
    if (active) {
#pragma unroll
      for (int kk = 0; kk < 2; kk++) {
#pragma unroll
        for (int nt = 0; nt < NT; nt++) {
          half8 b = *(const half8*)&wts[(nt * 16 + lrow) * LDW + kk * 32 + lch * 8];
          acc[nt] = __builtin_amdgcn_mfma_f32_16x16x32_f16(afrag[ph * 2 + kk], b, acc[nt], 0, 0, 0);
        }
      }
    }
    __syncthreads();
  }

  if (DO_ATT && active) {
    float asw[NT], adw[NT];
#pragma unroll
    for (int nt = 0; nt < NT; nt++) {
      asw[nt] = att_s[nt * 16 + lrow];
      adw[nt] = att_d[nt * 16 + lrow];
    }
#pragma unroll
    for (int h = 0; h < H; h++) {
#pragma unroll
      for (int reg = 0; reg < 4; reg++) {
        float ps = 0.f, pd = 0.f;
#pragma unroll
        for (int nt = h * NTH; nt < (h + 1) * NTH; nt++) {
          ps = fmaf(acc[nt][reg], asw[nt], ps);
          pd = fmaf(acc[nt][reg], adw[nt], pd);
        }
#pragma unroll
        for (int o = 1; o < 16; o <<= 1) {
          ps += __shfl_xor(ps, o);
          pd += __shfl_xor(pd, o);
        }
        if (lrow == 0) {
          int row = r0w + lch * 4 + reg;
          AS[row * H + h] = ps;
          AD[row * H + h] = pd;
        }
      }
    }
  }

  if (active) {
#pragma unroll
    for (int nt = 0; nt < NT; nt++) {
#pragma unroll
      for (int reg = 0; reg < 4; reg++) {
        ylds[w][(lch * 4 + reg) * LDY + nt * 16 + lrow] = __float2half(acc[nt][reg]);
      }
    }
  }
  __syncthreads();

  if (active) {
    constexpr int YCH = NOUT / 8;
    for (int idx = lane; idx < 16 * YCH; idx += 64) {
      int row = idx / YCH, ch = idx % YCH;
      uint4 v = *(const uint4*)&ylds[w][row * LDY + ch * 8];
      *(uint4*)(Y + (size_t)(r0w + row) * NOUT + ch * 8) = v;
    }
  }
}

// ---------------- build: bucket slabs -> exact CSR ----------------

template <int CAP>  // 12288
__global__ void build_kernel(const unsigned int* __restrict__ binned,
                             const int* __restrict__ cursor, int* __restrict__ offsets,
                             int* __restrict__ csr_src, int Nn, int Etot, int nbk, int capb) {
  __shared__ int nhist[256];
  __shared__ int sh[256];
  __shared__ int lcur[256];
  __shared__ int sbase, ssz;
  __shared__ unsigned short stage[CAP];
  int b = blockIdx.x;
  int t = threadIdx.x;

  int gv = (t < nbk) ? cursor[t] : 0;
  sh[t] = gv;
  __syncthreads();
  for (int o = 1; o < 256; o <<= 1) {
    int u = (t >= o) ? sh[t - o] : 0;
    __syncthreads();
    sh[t] += u;
    __syncthreads();
  }
  if (t == b) { sbase = sh[t] - gv; ssz = gv; }
  __syncthreads();
  int csrbase = sbase;
  int sz = ssz;
  int binbase = b * capb;

  nhist[t] = 0;
  __syncthreads();
  for (int i = t; i < sz; i += 256) atomicAdd(&nhist[binned[binbase + i] & 255], 1);
  __syncthreads();

  int hv = nhist[t];
  sh[t] = hv;
  __syncthreads();
  for (int o = 1; o < 256; o <<= 1) {
    int u = (t >= o) ? sh[t - o] : 0;
    __syncthreads();
    sh[t] += u;
    __syncthreads();
  }
  int excl = sh[t] - hv;
  int node = (b << 8) + t;
  if (node < Nn) offsets[node] = csrbase + excl;
  if (b == nbk - 1 && t == 0) offsets[Nn] = Etot;
  lcur[t] = excl;
  __syncthreads();

  if (sz <= CAP) {
    for (int i = t; i < sz; i += 256) {
      unsigned int v = binned[binbase + i];
      int lp = atomicAdd(&lcur[v & 255], 1);
      stage[lp] = (unsigned short)((v >> 8) & 0xFFFFu);
    }
    __syncthreads();
    for (int i = t; i < sz; i += 256) csr_src[csrbase + i] = (int)stage[i];
  } else {
    for (int i = t; i < sz; i += 256) {
      unsigned int v = binned[binbase + i];
      int lp = atomicAdd(&lcur[v & 255], 1);
      csr_src[csrbase + lp] = (int)((v >> 8) & 0xFFFFu);
    }
  }
}

// ---------------- node softmax + aggregate ----------------

static __device__ __forceinline__ void fma8(uint4 u, float e, float* __restrict__ acc) {
  float2 f0 = __half22float2(*(const __half2*)&u.x);
  float2 f1 = __half22float2(*(((const __half2*)&u.x) + 1));
  float2 f2 = __half22float2(*(const __half2*)&u.z);
  float2 f3 = __half22float2(*(((const __half2*)&u.z) + 1));
  acc[0] = fmaf(e, f0.x, acc[0]); acc[1] = fmaf(e, f0.y, acc[1]);
  acc[2] = fmaf(e, f1.x, acc[2]); acc[3] = fmaf(e, f1.y, acc[3]);
  acc[4] = fmaf(e, f2.x, acc[4]); acc[5] = fmaf(e, f2.y, acc[5]);
  acc[6] = fmaf(e, f3.x, acc[6]); acc[7] = fmaf(e, f3.y, acc[7]);
}

static __device__ __forceinline__ void pk4(uint4 u, unsigned ep, __half2* __restrict__ acc2) {
  __half2 e2 = *(const __half2*)&ep;
  acc2[0] = __hfma2(e2, *(const __half2*)&u.x, acc2[0]);
  acc2[1] = __hfma2(e2, *(((const __half2*)&u.x) + 1), acc2[1]);
  acc2[2] = __hfma2(e2, *(const __half2*)&u.z, acc2[2]);
  acc2[3] = __hfma2(e2, *(((const __half2*)&u.z) + 1), acc2[3]);
}

// One wave per node. H=2: 16 lanes/edge (lanes 0-7 head0, 8-15 head1); each edge
// visited once for both heads. H=1: 8 lanes/edge. FATT2: epilogue also emits
// as2[n]=h·vs2, ad2[n]=h·vd2 (layer-2 attention logits from the in-register row).
template <int H, bool RELU, bool FATT2, typename OT>
__global__ void node_kernel(const int* __restrict__ offsets, const int* __restrict__ csr_src,
                            const float* __restrict__ AS, const float* __restrict__ AD,
                            const __half* __restrict__ XPH, const float* __restrict__ bias,
                            OT* __restrict__ OUT, int Nn,
                            const float* __restrict__ vs2, const float* __restrict__ vd2,
                            float* __restrict__ as2o, float* __restrict__ ad2o) {
  constexpr int ROWH = H * 64;
  constexpr int LPE = (H == 2) ? 16 : 8;
  constexpr int G = 64 / LPE;
  int n = blockIdx.x;
  int lane = threadIdx.x & 63;
  int g = lane / LPE;
  int sub = lane & (LPE - 1);

  int beg = offsets[n], end = offsets[n + 1];
  int deg = end - beg;

  const __half* base = XPH + sub * 8;

  float acc[8];
#pragma unroll
  for (int k = 0; k < 8; k++) acc[k] = 0.f;
  float z0 = 0.f, z1 = 0.f;

  float ad0, ad1 = 0.f;
  if constexpr (H == 2) {
    float2 adn = ((const float2*)AD)[n];
    ad0 = adn.x; ad1 = adn.y;
  } else {
    ad0 = AD[n];
  }

  if constexpr (H == 2) {
    float2 asn = ((const float2*)AS)[n];
    float es0 = __expf(lrelu(asn.x + ad0));
    float es1 = __expf(lrelu(asn.y + ad1));
    if (g == 0) {
      uint4 u = *(const uint4*)(base + (size_t)n * ROWH);
      fma8(u, (lane & 8) ? es1 : es0, acc);
    }
    if (lane == 0) { z0 = es0; z1 = es1; }
  } else {
    float es = __expf(lrelu(AS[n] + ad0));
    if (g == 0) {
      uint4 u = *(const uint4*)(base + (size_t)n * ROWH);
      fma8(u, es, acc);
    }
    if (lane == 0) z0 = es;
  }

  for (int i0 = 0; i0 < deg; i0 += 64) {
    int cnt = min(64, deg - i0);
    int srcv = 0;
    int epk = 0;
    float ev0 = 0.f, ev1 = 0.f;
    if (lane < cnt) {
      srcv = csr_src[beg + i0 + lane];
      if constexpr (H == 2) {
        float2 asv = ((const float2*)AS)[srcv];
        ev0 = __expf(lrelu(asv.x + ad0));
        ev1 = __expf(lrelu(asv.y + ad1));
        __half h0 = __float2half(ev0), h1 = __float2half(ev1);
        epk = (int)(((unsigned)*(unsigned short*)&h1 << 16) | *(unsigned short*)&h0);
      } else {
        ev0 = __expf(lrelu(AS[srcv] + ad0));
        __half h0 = __float2half(ev0);
        unsigned short us = *(unsigned short*)&h0;
        epk = (int)(((unsigned)us << 16) | us);
      }
    }
    z0 += ev0;
    if constexpr (H == 2) z1 += ev1;

    auto sel = [&](int p) -> unsigned {
      unsigned short us;
      if constexpr (H == 2)
        us = (lane & 8) ? (unsigned short)((unsigned)p >> 16) : (unsigned short)((unsigned)p & 0xFFFFu);
      else
        us = (unsigned short)((unsigned)p & 0xFFFFu);
      return ((unsigned)us << 16) | us;
    };

    int j = 0;
    for (; j + 4 * G <= cnt; j += 4 * G) {
      int s0 = __shfl(srcv, j + g),         s1 = __shfl(srcv, j + G + g);
      int s2 = __shfl(srcv, j + 2 * G + g), s3 = __shfl(srcv, j + 3 * G + g);
      int p0 = __shfl(epk, j + g),          p1 = __shfl(epk, j + G + g);
      int p2 = __shfl(epk, j + 2 * G + g),  p3 = __shfl(epk, j + 3 * G + g);
      uint4 u0 = *(const uint4*)(base + (size_t)s0 * ROWH);
      uint4 u1 = *(const uint4*)(base + (size_t)s1 * ROWH);
      uint4 u2 = *(const uint4*)(base + (size_t)s2 * ROWH);
      uint4 u3 = *(const uint4*)(base + (size_t)s3 * ROWH);
      __half2 acc2[4];
      acc2[0] = __half2(__half(0.f), __half(0.f));
      acc2[1] = acc2[0]; acc2[2] = acc2[0]; acc2[3] = acc2[0];
      pk4(u0, sel(p0), acc2);
      pk4(u1, sel(p1), acc2);
      pk4(u2, sel(p2), acc2);
      pk4(u3, sel(p3), acc2);
#pragma unroll
      for (int k = 0; k < 4; k++) {
        float2 f = __half22float2(acc2[k]);
        acc[2 * k] += f.x;
        acc[2 * k + 1] += f.y;
      }
    }
    for (; j + G <= cnt; j += G) {
      int s = __shfl(srcv, j + g);
      int p = __shfl(epk, j + g);
      __half_raw hr; hr.x = (unsigned short)(sel(p) & 0xFFFFu);
      float e = __half2float(__half(hr));
      uint4 u = *(const uint4*)(base + (size_t)s * ROWH);
      fma8(u, e, acc);
    }
    if (j < cnt) {
      int idx = j + g;
      int s = __shfl(srcv, idx & 63);
      int p = __shfl(epk, idx & 63);
      if (idx < cnt) {
        __half_raw hr; hr.x = (unsigned short)(sel(p) & 0xFFFFu);
        float e = __half2float(__half(hr));
        uint4 u = *(const uint4*)(base + (size_t)s * ROWH);
        fma8(u, e, acc);
      }
    }
  }

#pragma unroll
  for (int o = LPE; o <= 32; o <<= 1) {
#pragma unroll
    for (int k = 0; k < 8; k++) acc[k] += __shfl_xor(acc[k], o);
  }
  for (int o = 32; o > 0; o >>= 1) {
    z0 += __shfl_xor(z0, o);
    if constexpr (H == 2) z1 += __shfl_xor(z1, o);
  }
  float inv;
  if constexpr (H == 2) inv = 1.0f / ((lane & 8) ? z1 : z0);
  else inv = 1.0f / z0;

  if (g == 0) {
    const float* bp = bias + sub * 8;
    float r[8];
#pragma unroll
    for (int k = 0; k < 8; k++) {
      r[k] = fmaf(acc[k], inv, bp[k]);
      if (RELU) r[k] = fmaxf(r[k], 0.f);
    }
    if constexpr (FATT2) {
      // layer-2 attention logits from the in-register h row
      float ps = 0.f, pd = 0.f;
#pragma unroll
      for (int k = 0; k < 8; k++) {
        ps = fmaf(r[k], vs2[sub * 8 + k], ps);
        pd = fmaf(r[k], vd2[sub * 8 + k], pd);
      }
#pragma unroll
      for (int o = 1; o < 16; o <<= 1) {
        ps += __shfl_xor(ps, o);
        pd += __shfl_xor(pd, o);
      }
      if (lane == 0) { as2o[n] = ps; ad2o[n] = pd; }
    }
    if constexpr (sizeof(OT) == 4) {
      float* op = (float*)OUT + (size_t)n * ROWH + sub * 8;
      ((float4*)op)[0] = make_float4(r[0], r[1], r[2], r[3]);
      ((float4*)op)[1] = make_float4(r[4], r[5], r[6], r[7]);
    } else {
      __half* op = (__half*)OUT + (size_t)n * ROWH + sub * 8;
      __half2 h0 = __floats2half2_rn(r[0], r[1]);
      __half2 h1 = __floats2half2_rn(r[2], r[3]);
      __half2 h2 = __floats2half2_rn(r[4], r[5]);
      __half2 h3 = __floats2half2_rn(r[6], r[7]);
      uint4 u;
      u.x = *(unsigned int*)&h0; u.y = *(unsigned int*)&h1;
      u.z = *(unsigned int*)&h2; u.w = *(unsigned int*)&h3;
      *(uint4*)op = u;
    }
  }
}

// ---------------- launch ----------------

static inline size_t alignup(size_t x) { return (x + 255) & ~(size_t)255; }

extern "C" void kernel_launch(void* const* d_in, const int* in_sizes, int n_in,
                              void* d_out, int out_size, void* d_ws, size_t ws_size,
                              hipStream_t stream) {
  const float* x    = (const float*)d_in[0];
  const int*   edges= (const int*)d_in[1];
  const float* W1   = (const float*)d_in[2];
  const float* as1w = (const float*)d_in[3];
  const float* ad1w = (const float*)d_in[4];
  const float* b1   = (const float*)d_in[5];
  const float* W2   = (const float*)d_in[6];
  const float* as2w = (const float*)d_in[7];
  const float* ad2w = (const float*)d_in[8];
  const float* b2   = (const float*)d_in[9];

  const int N = in_sizes[0] / 128;   // 50000
  const int E = in_sizes[1] / 2;     // 1600000
  const int* src = edges;
  const int* dst = edges + E;
  const int nbk = (N + 255) >> 8;    // 196 buckets

  constexpr int CHUNK = 2048;
  constexpr int CAPB = 10240;        // slab capacity per bucket

  char* p = (char*)d_ws;
  size_t off = 0;
  auto take = [&](size_t bytes) { char* r = p + off; off = alignup(off + bytes); return r; };
  __half* xph1 = (__half*)take((size_t)N * 128 * 2);  // row-major [N][128]
  __half* xph2 = (__half*)take((size_t)N * 64 * 2);
  __half* hbuf = (__half*)take((size_t)N * 128 * 2);
  float* as1   = (float*)take((size_t)N * 2 * 4);
  float* ad1   = (float*)take((size_t)N * 2 * 4);
  float* as2   = (float*)take((size_t)N * 4);
  float* ad2   = (float*)take((size_t)N * 4);
  float* vs2   = (float*)take(128 * 4);
  float* vd2   = (float*)take(128 * 4);
  int* offsets = (int*)take((size_t)(N + 1) * 4);
  int* csr_src = (int*)take((size_t)E * 4);
  unsigned int* binned = (unsigned int*)take((size_t)nbk * CAPB * 4);
  int* cursor  = (int*)take((size_t)NBK_MAX * 4);
  (void)ws_size;

  const int binBlocks = (E + CHUNK - 1) / CHUNK;   // 782
  const int gemmBlocks = (N + 63) / 64;            // 782

  hipMemsetAsync(cursor, 0, (size_t)NBK_MAX * 4, stream);

  // MEGA: gemm1 [0,gemmBlocks) + bin [gemmBlocks, +binBlocks) + v2 block (last)
  gemm_bin_mfma<128, 128, 2, true, true, CHUNK, float>
      <<<gemmBlocks + binBlocks + 1, 256, 0, stream>>>(
      x, W1, as1w, ad1w, xph1, as1, ad1, N, gemmBlocks,
      src, dst, cursor, binned, E, nbk, CAPB,
      W2, as2w, ad2w, vs2, vd2);

  build_kernel<12288><<<nbk, 256, 0, stream>>>(binned, cursor, offsets, csr_src, N, E, nbk, CAPB);

  // layer 1 node aggregation (merged heads) + fused layer-2 logits
  node_kernel<2, true, true, __half><<<N, 64, 0, stream>>>(
      offsets, csr_src, as1, ad1, xph1, b1, hbuf, N, vs2, vd2, as2, ad2);

  // layer 2: plain GEMM (no attention epilogue), then aggregation
  gemm_bin_mfma<128, 64, 1, false, false, CHUNK, __half><<<gemmBlocks, 256, 0, stream>>>(
      hbuf, W2, as2w, ad2w, xph2, as2, ad2, N, gemmBlocks,
      nullptr, nullptr, nullptr, nullptr, 0, nbk, CAPB,
      nullptr, nullptr, nullptr, nullptr, nullptr);
  node_kernel<1, false, false, float><<<N, 64, 0, stream>>>(
      offsets, csr_src, as2, ad2, xph2, b2, (float*)d_out, N,
      nullptr, nullptr, nullptr, nullptr);
}

// Round 14
// 139.934 us; speedup vs baseline: 1.0922x; 1.0922x over previous
//
#include <hip/hip_runtime.h>
#include <hip/hip_bf16.h>
#include <hip/hip_fp16.h>

// GAT 2-layer forward for MI355X — round 14.
// r13 regressed (K-split staging + FATT2 epilogue both negative) -> revert to
// the r12 structure. Deltas vs r12 (CSR path only):
//  - bin CHUNK 2048->4096: halves the 196-address global cursor contention
//    (one atomic per bucket per block) and halves scan count.
//  - bin/build 256-wide scans replaced by wave-shuffle scans (2 barriers
//    instead of 16 per scan) -> shorter critical path in latency-bound build.

#define SLOPE 0.2f
static __device__ __forceinline__ float lrelu(float a) { return a > 0.f ? a : SLOPE * a; }

#define NBK_MAX 256  // max buckets (N <= 65536)

typedef _Float16 half8 __attribute__((ext_vector_type(8)));
typedef float f32x4 __attribute__((ext_vector_type(4)));

// inclusive scan of 256 per-thread ints; scratch = 8 ints in LDS; 2 barriers.
static __device__ __forceinline__ int scan256(int v, int* __restrict__ scratch) {
  int lane = threadIdx.x & 63;
  int wv = threadIdx.x >> 6;
  for (int o = 1; o < 64; o <<= 1) {
    int u = __shfl_up(v, o);
    if (lane >= o) v += u;
  }
  if (lane == 63) scratch[wv] = v;
  __syncthreads();
  if (wv == 0 && lane < 4) {
    int s = scratch[lane];
    for (int o = 1; o < 4; o <<= 1) {
      int u = __shfl_up(s, o, 4);
      if ((lane & 3) >= o) s += u;
    }
    scratch[4 + lane] = s;
  }
  __syncthreads();
  return v + ((wv > 0) ? scratch[4 + wv - 1] : 0);
}

// ---------------- MEGA: MFMA GEMM + fused attention dots (+ fused bin) ----------------

// W fp32 [K][NOUT] row-major; transposed+converted into LDS per block (single
// stage, r12 structure). FUSE_BIN: blocks >= gemmBlocks bin edges into
// fixed-stride bucket slabs binned[b*capb + atomic-reserved range].
template <int K, int NOUT, int H, bool FUSE_BIN, int CHUNK, typename AT>
__global__ __launch_bounds__(256) void gemm_bin_mfma(
    const AT* __restrict__ A, const float* __restrict__ Wg,
    const float* __restrict__ att_s, const float* __restrict__ att_d,
    __half* __restrict__ Y, float* __restrict__ AS, float* __restrict__ AD,
    int M, int gemmBlocks,
    const int* __restrict__ srcArr, const int* __restrict__ dstArr,
    int* __restrict__ cursor, unsigned int* __restrict__ binned,
    int E2, int nbk, int capb) {
  constexpr int KK = K / 32;
  constexpr int NT = NOUT / 16;
  constexpr int NTH = NT / H;
  constexpr int LDW = K + 8;
  constexpr int LDY = NOUT + 8;
  constexpr int WTS_B = NOUT * LDW * 2;
  constexpr int YLDS_B = 4 * 16 * LDY * 2;
  constexpr int GEMM_B = (WTS_B > YLDS_B) ? WTS_B : YLDS_B;  // ylds aliases wts
  constexpr int BIN_B = 4 * 256 * 4 + 8 * 4 + CHUNK * 4;
  constexpr int SMEM_B = (FUSE_BIN && BIN_B > GEMM_B) ? BIN_B : GEMM_B;
  __shared__ __align__(16) char smem[SMEM_B];

  int tid = threadIdx.x;

  if constexpr (FUSE_BIN) {
    if ((int)blockIdx.x >= gemmBlocks) {
      // ---- bin branch ----
      int* hist = (int*)smem;
      int* lbase = hist + 256;
      int* lcur = lbase + 256;
      int* gpos = lcur + 256;
      int* shws = gpos + 256;  // 8 ints
      unsigned int* stage = (unsigned int*)(shws + 8);
      constexpr int PT = CHUNK / 256;
      int t = tid;
      int bb = blockIdx.x - gemmBlocks;
      int e0 = bb * CHUNK;
      int cnt = min(CHUNK, E2 - e0);

      hist[t] = 0;
      __syncthreads();

      unsigned int pk[PT];
#pragma unroll
      for (int i = 0; i < PT; i++) {
        int e = e0 + t + i * 256;
        if (e < E2) {
          int s = srcArr[e], d = dstArr[e];
          int b = d >> 8;
          pk[i] = ((unsigned)b << 24) | ((unsigned)s << 8) | (unsigned)(d & 255);
          atomicAdd(&hist[b], 1);
        } else {
          pk[i] = 0xFFFFFFFFu;
        }
      }
      __syncthreads();

      int hv = hist[t];
      int incl = scan256(hv, shws);
      lbase[t] = incl - hv;
      lcur[t] = incl - hv;
      gpos[t] = hv ? (t * capb + atomicAdd(&cursor[t], hv)) : 0;
      __syncthreads();

#pragma unroll
      for (int i = 0; i < PT; i++) {
        if (pk[i] != 0xFFFFFFFFu) {
          int b = pk[i] >> 24;
          int lp = atomicAdd(&lcur[b], 1);
          stage[lp] = pk[i];
        }
      }
      __syncthreads();

      for (int i = t; i < cnt; i += 256) {
        unsigned int v = stage[i];
        int b = v >> 24;
        binned[gpos[b] + (i - lbase[b])] = v;
      }
      return;
    }
  }

  // ---- gemm branch (r12 structure: single-stage W^T, ylds aliased) ----
  __half* wts = (__half*)smem;
  __half(*ylds)[16 * LDY] = (__half(*)[16 * LDY])smem;

  int w = tid >> 6;
  int lane = tid & 63;
  int lrow = lane & 15;
  int lch = lane >> 4;
  int r0w = blockIdx.x * 64 + w * 16;
  bool active = (r0w < M);

  for (int idx = tid; idx < NOUT * K; idx += 256) {
    int k = idx / NOUT, c = idx - k * NOUT;
    wts[c * LDW + k] = __float2half(Wg[idx]);
  }
  __syncthreads();

  f32x4 acc[NT];
#pragma unroll
  for (int nt = 0; nt < NT; nt++) acc[nt] = (f32x4){0.f, 0.f, 0.f, 0.f};

  if (active) {
    half8 afrag[KK];
    if constexpr (sizeof(AT) == 4) {
      const float* arow = (const float*)A + (size_t)(r0w + lrow) * K + lch * 8;
#pragma unroll
      for (int kk = 0; kk < KK; kk++) {
        float4 v0 = *(const float4*)(arow + kk * 32);
        float4 v1 = *(const float4*)(arow + kk * 32 + 4);
        half8 a;
        a[0] = (_Float16)v0.x; a[1] = (_Float16)v0.y;
        a[2] = (_Float16)v0.z; a[3] = (_Float16)v0.w;
        a[4] = (_Float16)v1.x; a[5] = (_Float16)v1.y;
        a[6] = (_Float16)v1.z; a[7] = (_Float16)v1.w;
        afrag[kk] = a;
      }
    } else {
      const __half* arow = (const __half*)A + (size_t)(r0w + lrow) * K + lch * 8;
#pragma unroll
      for (int kk = 0; kk < KK; kk++) afrag[kk] = *(const half8*)(arow + kk * 32);
    }

#pragma unroll
    for (int kk = 0; kk < KK; kk++) {
#pragma unroll
      for (int nt = 0; nt < NT; nt++) {
        half8 b = *(const half8*)&wts[(nt * 16 + lrow) * LDW + kk * 32 + lch * 8];
        acc[nt] = __builtin_amdgcn_mfma_f32_16x16x32_f16(afrag[kk], b, acc[nt], 0, 0, 0);
      }
    }

    float asw[NT], adw[NT];
#pragma unroll
    for (int nt = 0; nt < NT; nt++) {
      asw[nt] = att_s[nt * 16 + lrow];
      adw[nt] = att_d[nt * 16 + lrow];
    }
#pragma unroll
    for (int h = 0; h < H; h++) {
#pragma unroll
      for (int reg = 0; reg < 4; reg++) {
        float ps = 0.f, pd = 0.f;
#pragma unroll
        for (int nt = h * NTH; nt < (h + 1) * NTH; nt++) {
          ps = fmaf(acc[nt][reg], asw[nt], ps);
          pd = fmaf(acc[nt][reg], adw[nt], pd);
        }
#pragma unroll
        for (int o = 1; o < 16; o <<= 1) {
          ps += __shfl_xor(ps, o);
          pd += __shfl_xor(pd, o);
        }
        if (lrow == 0) {
          int row = r0w + lch * 4 + reg;
          AS[row * H + h] = ps;
          AD[row * H + h] = pd;
        }
      }
    }
  }

  __syncthreads();  // wts dead; ylds may overwrite

  if (active) {
#pragma unroll
    for (int nt = 0; nt < NT; nt++) {
#pragma unroll
      for (int reg = 0; reg < 4; reg++) {
        ylds[w][(lch * 4 + reg) * LDY + nt * 16 + lrow] = __float2half(acc[nt][reg]);
      }
    }
  }
  __syncthreads();

  if (active) {
    constexpr int YCH = NOUT / 8;
    for (int idx = lane; idx < 16 * YCH; idx += 64) {
      int row = idx / YCH, ch = idx % YCH;
      uint4 v = *(const uint4*)&ylds[w][row * LDY + ch * 8];
      *(uint4*)(Y + (size_t)(r0w + row) * NOUT + ch * 8) = v;
    }
  }
}

// ---------------- build: bucket slabs -> exact CSR ----------------

template <int CAP>  // 12288
__global__ void build_kernel(const unsigned int* __restrict__ binned,
                             const int* __restrict__ cursor, int* __restrict__ offsets,
                             int* __restrict__ csr_src, int Nn, int Etot, int nbk, int capb) {
  __shared__ int nhist[256];
  __shared__ int lcur[256];
  __shared__ int shws[8];
  __shared__ int sbase, ssz;
  __shared__ unsigned short stage[CAP];
  int b = blockIdx.x;
  int t = threadIdx.x;

  // scan final bucket counts -> this bucket's CSR base/size (wave-shuffle scan)
  int gv = (t < nbk) ? cursor[t] : 0;
  int incl = scan256(gv, shws);
  if (t == b) { sbase = incl - gv; ssz = gv; }
  __syncthreads();
  int csrbase = sbase;
  int sz = ssz;
  int binbase = b * capb;

  nhist[t] = 0;
  __syncthreads();
  for (int i = t; i < sz; i += 256) atomicAdd(&nhist[binned[binbase + i] & 255], 1);
  __syncthreads();

  int hv = nhist[t];
  int incl2 = scan256(hv, shws);
  int excl = incl2 - hv;
  int node = (b << 8) + t;
  if (node < Nn) offsets[node] = csrbase + excl;
  if (b == nbk - 1 && t == 0) offsets[Nn] = Etot;
  lcur[t] = excl;
  __syncthreads();

  if (sz <= CAP) {
    for (int i = t; i < sz; i += 256) {
      unsigned int v = binned[binbase + i];
      int lp = atomicAdd(&lcur[v & 255], 1);
      stage[lp] = (unsigned short)((v >> 8) & 0xFFFFu);
    }
    __syncthreads();
    for (int i = t; i < sz; i += 256) csr_src[csrbase + i] = (int)stage[i];
  } else {
    for (int i = t; i < sz; i += 256) {
      unsigned int v = binned[binbase + i];
      int lp = atomicAdd(&lcur[v & 255], 1);
      csr_src[csrbase + lp] = (int)((v >> 8) & 0xFFFFu);
    }
  }
}

// ---------------- node softmax + aggregate ----------------

static __device__ __forceinline__ void fma8(uint4 u, float e, float* __restrict__ acc) {
  float2 f0 = __half22float2(*(const __half2*)&u.x);
  float2 f1 = __half22float2(*(((const __half2*)&u.x) + 1));
  float2 f2 = __half22float2(*(const __half2*)&u.z);
  float2 f3 = __half22float2(*(((const __half2*)&u.z) + 1));
  acc[0] = fmaf(e, f0.x, acc[0]); acc[1] = fmaf(e, f0.y, acc[1]);
  acc[2] = fmaf(e, f1.x, acc[2]); acc[3] = fmaf(e, f1.y, acc[3]);
  acc[4] = fmaf(e, f2.x, acc[4]); acc[5] = fmaf(e, f2.y, acc[5]);
  acc[6] = fmaf(e, f3.x, acc[6]); acc[7] = fmaf(e, f3.y, acc[7]);
}

static __device__ __forceinline__ void pk4(uint4 u, unsigned ep, __half2* __restrict__ acc2) {
  __half2 e2 = *(const __half2*)&ep;
  acc2[0] = __hfma2(e2, *(const __half2*)&u.x, acc2[0]);
  acc2[1] = __hfma2(e2, *(((const __half2*)&u.x) + 1), acc2[1]);
  acc2[2] = __hfma2(e2, *(const __half2*)&u.z, acc2[2]);
  acc2[3] = __hfma2(e2, *(((const __half2*)&u.z) + 1), acc2[3]);
}

// One wave per node. H=2: 16 lanes/edge (lanes 0-7 head0, 8-15 head1); each edge
// visited once for both heads. H=1: 8 lanes/edge.
template <int H, bool RELU, typename OT>
__global__ void node_kernel(const int* __restrict__ offsets, const int* __restrict__ csr_src,
                            const float* __restrict__ AS, const float* __restrict__ AD,
                            const __half* __restrict__ XPH, const float* __restrict__ bias,
                            OT* __restrict__ OUT, int Nn) {
  constexpr int ROWH = H * 64;
  constexpr int LPE = (H == 2) ? 16 : 8;
  constexpr int G = 64 / LPE;
  int n = blockIdx.x;
  int lane = threadIdx.x & 63;
  int g = lane / LPE;
  int sub = lane & (LPE - 1);

  int beg = offsets[n], end = offsets[n + 1];
  int deg = end - beg;

  const __half* base = XPH + sub * 8;

  float acc[8];
#pragma unroll
  for (int k = 0; k < 8; k++) acc[k] = 0.f;
  float z0 = 0.f, z1 = 0.f;

  float ad0, ad1 = 0.f;
  if constexpr (H == 2) {
    float2 adn = ((const float2*)AD)[n];
    ad0 = adn.x; ad1 = adn.y;
  } else {
    ad0 = AD[n];
  }

  if constexpr (H == 2) {
    float2 asn = ((const float2*)AS)[n];
    float es0 = __expf(lrelu(asn.x + ad0));
    float es1 = __expf(lrelu(asn.y + ad1));
    if (g == 0) {
      uint4 u = *(const uint4*)(base + (size_t)n * ROWH);
      fma8(u, (lane & 8) ? es1 : es0, acc);
    }
    if (lane == 0) { z0 = es0; z1 = es1; }
  } else {
    float es = __expf(lrelu(AS[n] + ad0));
    if (g == 0) {
      uint4 u = *(const uint4*)(base + (size_t)n * ROWH);
      fma8(u, es, acc);
    }
    if (lane == 0) z0 = es;
  }

  for (int i0 = 0; i0 < deg; i0 += 64) {
    int cnt = min(64, deg - i0);
    int srcv = 0;
    int epk = 0;
    float ev0 = 0.f, ev1 = 0.f;
    if (lane < cnt) {
      srcv = csr_src[beg + i0 + lane];
      if constexpr (H == 2) {
        float2 asv = ((const float2*)AS)[srcv];
        ev0 = __expf(lrelu(asv.x + ad0));
        ev1 = __expf(lrelu(asv.y + ad1));
        __half h0 = __float2half(ev0), h1 = __float2half(ev1);
        epk = (int)(((unsigned)*(unsigned short*)&h1 << 16) | *(unsigned short*)&h0);
      } else {
        ev0 = __expf(lrelu(AS[srcv] + ad0));
        __half h0 = __float2half(ev0);
        unsigned short us = *(unsigned short*)&h0;
        epk = (int)(((unsigned)us << 16) | us);
      }
    }
    z0 += ev0;
    if constexpr (H == 2) z1 += ev1;

    auto sel = [&](int p) -> unsigned {
      unsigned short us;
      if constexpr (H == 2)
        us = (lane & 8) ? (unsigned short)((unsigned)p >> 16) : (unsigned short)((unsigned)p & 0xFFFFu);
      else
        us = (unsigned short)((unsigned)p & 0xFFFFu);
      return ((unsigned)us << 16) | us;
    };

    int j = 0;
    for (; j + 4 * G <= cnt; j += 4 * G) {
      int s0 = __shfl(srcv, j + g),         s1 = __shfl(srcv, j + G + g);
      int s2 = __shfl(srcv, j + 2 * G + g), s3 = __shfl(srcv, j + 3 * G + g);
      int p0 = __shfl(epk, j + g),          p1 = __shfl(epk, j + G + g);
      int p2 = __shfl(epk, j + 2 * G + g),  p3 = __shfl(epk, j + 3 * G + g);
      uint4 u0 = *(const uint4*)(base + (size_t)s0 * ROWH);
      uint4 u1 = *(const uint4*)(base + (size_t)s1 * ROWH);
      uint4 u2 = *(const uint4*)(base + (size_t)s2 * ROWH);
      uint4 u3 = *(const uint4*)(base + (size_t)s3 * ROWH);
      __half2 acc2[4];
      acc2[0] = __half2(__half(0.f), __half(0.f));
      acc2[1] = acc2[0]; acc2[2] = acc2[0]; acc2[3] = acc2[0];
      pk4(u0, sel(p0), acc2);
      pk4(u1, sel(p1), acc2);
      pk4(u2, sel(p2), acc2);
      pk4(u3, sel(p3), acc2);
#pragma unroll
      for (int k = 0; k < 4; k++) {
        float2 f = __half22float2(acc2[k]);
        acc[2 * k] += f.x;
        acc[2 * k + 1] += f.y;
      }
    }
    for (; j + G <= cnt; j += G) {
      int s = __shfl(srcv, j + g);
      int p = __shfl(epk, j + g);
      __half_raw hr; hr.x = (unsigned short)(sel(p) & 0xFFFFu);
      float e = __half2float(__half(hr));
      uint4 u = *(const uint4*)(base + (size_t)s * ROWH);
      fma8(u, e, acc);
    }
    if (j < cnt) {
      int idx = j + g;
      int s = __shfl(srcv, idx & 63);
      int p = __shfl(epk, idx & 63);
      if (idx < cnt) {
        __half_raw hr; hr.x = (unsigned short)(sel(p) & 0xFFFFu);
        float e = __half2float(__half(hr));
        uint4 u = *(const uint4*)(base + (size_t)s * ROWH);
        fma8(u, e, acc);
      }
    }
  }

#pragma unroll
  for (int o = LPE; o <= 32; o <<= 1) {
#pragma unroll
    for (int k = 0; k < 8; k++) acc[k] += __shfl_xor(acc[k], o);
  }
  for (int o = 32; o > 0; o >>= 1) {
    z0 += __shfl_xor(z0, o);
    if constexpr (H == 2) z1 += __shfl_xor(z1, o);
  }
  float inv;
  if constexpr (H == 2) inv = 1.0f / ((lane & 8) ? z1 : z0);
  else inv = 1.0f / z0;

  if (g == 0) {
    const float* bp = bias + sub * 8;
    float r[8];
#pragma unroll
    for (int k = 0; k < 8; k++) {
      r[k] = fmaf(acc[k], inv, bp[k]);
      if (RELU) r[k] = fmaxf(r[k], 0.f);
    }
    if constexpr (sizeof(OT) == 4) {
      float* op = (float*)OUT + (size_t)n * ROWH + sub * 8;
      ((float4*)op)[0] = make_float4(r[0], r[1], r[2], r[3]);
      ((float4*)op)[1] = make_float4(r[4], r[5], r[6], r[7]);
    } else {
      __half* op = (__half*)OUT + (size_t)n * ROWH + sub * 8;
      __half2 h0 = __floats2half2_rn(r[0], r[1]);
      __half2 h1 = __floats2half2_rn(r[2], r[3]);
      __half2 h2 = __floats2half2_rn(r[4], r[5]);
      __half2 h3 = __floats2half2_rn(r[6], r[7]);
      uint4 u;
      u.x = *(unsigned int*)&h0; u.y = *(unsigned int*)&h1;
      u.z = *(unsigned int*)&h2; u.w = *(unsigned int*)&h3;
      *(uint4*)op = u;
    }
  }
}

// ---------------- launch ----------------

static inline size_t alignup(size_t x) { return (x + 255) & ~(size_t)255; }

extern "C" void kernel_launch(void* const* d_in, const int* in_sizes, int n_in,
                              void* d_out, int out_size, void* d_ws, size_t ws_size,
                              hipStream_t stream) {
  const float* x    = (const float*)d_in[0];
  const int*   edges= (const int*)d_in[1];
  const float* W1   = (const float*)d_in[2];
  const float* as1w = (const float*)d_in[3];
  const float* ad1w = (const float*)d_in[4];
  const float* b1   = (const float*)d_in[5];
  const float* W2   = (const float*)d_in[6];
  const float* as2w = (const float*)d_in[7];
  const float* ad2w = (const float*)d_in[8];
  const float* b2   = (const float*)d_in[9];

  const int N = in_sizes[0] / 128;   // 50000
  const int E = in_sizes[1] / 2;     // 1600000
  const int* src = edges;
  const int* dst = edges + E;
  const int nbk = (N + 255) >> 8;    // 196 buckets

  constexpr int CHUNK = 4096;
  constexpr int CAPB = 10240;        // slab capacity per bucket

  char* p = (char*)d_ws;
  size_t off = 0;
  auto take = [&](size_t bytes) { char* r = p + off; off = alignup(off + bytes); return r; };
  __half* xph1 = (__half*)take((size_t)N * 128 * 2);  // row-major [N][128]
  __half* xph2 = (__half*)take((size_t)N * 64 * 2);
  __half* hbuf = (__half*)take((size_t)N * 128 * 2);
  float* as1   = (float*)take((size_t)N * 2 * 4);
  float* ad1   = (float*)take((size_t)N * 2 * 4);
  float* as2   = (float*)take((size_t)N * 4);
  float* ad2   = (float*)take((size_t)N * 4);
  int* offsets = (int*)take((size_t)(N + 1) * 4);
  int* csr_src = (int*)take((size_t)E * 4);
  unsigned int* binned = (unsigned int*)take((size_t)nbk * CAPB * 4);
  int* cursor  = (int*)take((size_t)NBK_MAX * 4);
  (void)ws_size;

  const int binBlocks = (E + CHUNK - 1) / CHUNK;   // 391
  const int gemmBlocks = (N + 63) / 64;            // 782

  hipMemsetAsync(cursor, 0, (size_t)NBK_MAX * 4, stream);

  // MEGA: gemm1 blocks [0,gemmBlocks) + bin blocks [gemmBlocks, +binBlocks)
  gemm_bin_mfma<128, 128, 2, true, CHUNK, float><<<gemmBlocks + binBlocks, 256, 0, stream>>>(
      x, W1, as1w, ad1w, xph1, as1, ad1, N, gemmBlocks,
      src, dst, cursor, binned, E, nbk, CAPB);

  build_kernel<12288><<<nbk, 256, 0, stream>>>(binned, cursor, offsets, csr_src, N, E, nbk, CAPB);

  // layer 1 node aggregation (merged heads)
  node_kernel<2, true, __half><<<N, 64, 0, stream>>>(
      offsets, csr_src, as1, ad1, xph1, b1, hbuf, N);

  // layer 2
  gemm_bin_mfma<128, 64, 1, false, CHUNK, __half><<<gemmBlocks, 256, 0, stream>>>(
      hbuf, W2, as2w, ad2w, xph2, as2, ad2, N, gemmBlocks,
      nullptr, nullptr, nullptr, nullptr, 0, nbk, CAPB);
  node_kernel<1, false, float><<<N, 64, 0, stream>>>(
      offsets, csr_src, as2, ad2, xph2, b2, (float*)d_out, N);
}

// Round 15
// 138.260 us; speedup vs baseline: 1.1054x; 1.0121x over previous
//
#include <hip/hip_runtime.h>
#include <hip/hip_bf16.h>
#include <hip/hip_fp16.h>

// GAT 2-layer forward for MI355X — round 15.
// Deltas vs round 14 (both low-risk):
//  - bin branch: per-wave LDS histograms + per-wave scatter cursors (4 private
//    copies, bases chained at scan) -> no cross-wave LDS-atomic serialization.
//  - node kernels: bijective XCD swizzle (N%8==0 path) so each XCD streams a
//    contiguous csr_src/offsets range through its private L2.

#define SLOPE 0.2f
static __device__ __forceinline__ float lrelu(float a) { return a > 0.f ? a : SLOPE * a; }

#define NBK_MAX 256  // max buckets (N <= 65536)

typedef _Float16 half8 __attribute__((ext_vector_type(8)));
typedef float f32x4 __attribute__((ext_vector_type(4)));

// bijective XCD-aware block->work mapping (identity if nwg % 8 != 0)
static __device__ __forceinline__ int xcd_swz(int bid, int nwg) {
  if (nwg & 7) return bid;
  int cpx = nwg >> 3;
  return (bid & 7) * cpx + (bid >> 3);
}

// inclusive scan of 256 per-thread ints; scratch = 8 ints in LDS; 2 barriers.
static __device__ __forceinline__ int scan256(int v, int* __restrict__ scratch) {
  int lane = threadIdx.x & 63;
  int wv = threadIdx.x >> 6;
  for (int o = 1; o < 64; o <<= 1) {
    int u = __shfl_up(v, o);
    if (lane >= o) v += u;
  }
  if (lane == 63) scratch[wv] = v;
  __syncthreads();
  if (wv == 0 && lane < 4) {
    int s = scratch[lane];
    for (int o = 1; o < 4; o <<= 1) {
      int u = __shfl_up(s, o, 4);
      if ((lane & 3) >= o) s += u;
    }
    scratch[4 + lane] = s;
  }
  __syncthreads();
  return v + ((wv > 0) ? scratch[4 + wv - 1] : 0);
}

// ---------------- MEGA: MFMA GEMM + fused attention dots (+ fused bin) ----------------

template <int K, int NOUT, int H, bool FUSE_BIN, int CHUNK, typename AT>
__global__ __launch_bounds__(256) void gemm_bin_mfma(
    const AT* __restrict__ A, const float* __restrict__ Wg,
    const float* __restrict__ att_s, const float* __restrict__ att_d,
    __half* __restrict__ Y, float* __restrict__ AS, float* __restrict__ AD,
    int M, int gemmBlocks,
    const int* __restrict__ srcArr, const int* __restrict__ dstArr,
    int* __restrict__ cursor, unsigned int* __restrict__ binned,
    int E2, int nbk, int capb) {
  constexpr int KK = K / 32;
  constexpr int NT = NOUT / 16;
  constexpr int NTH = NT / H;
  constexpr int LDW = K + 8;
  constexpr int LDY = NOUT + 8;
  constexpr int WTS_B = NOUT * LDW * 2;
  constexpr int YLDS_B = 4 * 16 * LDY * 2;
  constexpr int GEMM_B = (WTS_B > YLDS_B) ? WTS_B : YLDS_B;  // ylds aliases wts
  constexpr int BIN_B = (1024 + 1024 + 256 + 256 + 8) * 4 + CHUNK * 4;
  constexpr int SMEM_B = (FUSE_BIN && BIN_B > GEMM_B) ? BIN_B : GEMM_B;
  __shared__ __align__(16) char smem[SMEM_B];

  int tid = threadIdx.x;

  if constexpr (FUSE_BIN) {
    if ((int)blockIdx.x >= gemmBlocks) {
      // ---- bin branch (per-wave hist + per-wave cursors) ----
      int* hist4 = (int*)smem;           // [4][256]
      int* lcurw = hist4 + 1024;         // [4][256]
      int* lbase = lcurw + 1024;         // [256]
      int* gpos = lbase + 256;           // [256]
      int* shws = gpos + 256;            // 8
      unsigned int* stage = (unsigned int*)(shws + 8);
      constexpr int PT = CHUNK / 256;
      int t = tid;
      int wv = t >> 6;
      int bb = blockIdx.x - gemmBlocks;
      int e0 = bb * CHUNK;
      int cnt = min(CHUNK, E2 - e0);

#pragma unroll
      for (int c = 0; c < 4; c++) hist4[c * 256 + t] = 0;
      __syncthreads();

      unsigned int pk[PT];
#pragma unroll
      for (int i = 0; i < PT; i++) {
        int e = e0 + t + i * 256;
        if (e < E2) {
          int s = srcArr[e], d = dstArr[e];
          int b = d >> 8;
          pk[i] = ((unsigned)b << 24) | ((unsigned)s << 8) | (unsigned)(d & 255);
          atomicAdd(&hist4[wv * 256 + b], 1);
        } else {
          pk[i] = 0xFFFFFFFFu;
        }
      }
      __syncthreads();

      int h0 = hist4[t], h1 = hist4[256 + t], h2 = hist4[512 + t], h3 = hist4[768 + t];
      int hv = h0 + h1 + h2 + h3;
      int incl = scan256(hv, shws);
      int bexcl = incl - hv;
      lbase[t] = bexcl;
      lcurw[t] = bexcl;                       // wave 0 base
      lcurw[256 + t] = bexcl + h0;            // wave 1
      lcurw[512 + t] = bexcl + h0 + h1;       // wave 2
      lcurw[768 + t] = bexcl + h0 + h1 + h2;  // wave 3
      gpos[t] = hv ? (t * capb + atomicAdd(&cursor[t], hv)) : 0;
      __syncthreads();

#pragma unroll
      for (int i = 0; i < PT; i++) {
        if (pk[i] != 0xFFFFFFFFu) {
          int b = pk[i] >> 24;
          int lp = atomicAdd(&lcurw[wv * 256 + b], 1);
          stage[lp] = pk[i];
        }
      }
      __syncthreads();

      for (int i = t; i < cnt; i += 256) {
        unsigned int v = stage[i];
        int b = v >> 24;
        binned[gpos[b] + (i - lbase[b])] = v;
      }
      return;
    }
  }

  // ---- gemm branch (single-stage W^T, ylds aliased) ----
  __half* wts = (__half*)smem;
  __half(*ylds)[16 * LDY] = (__half(*)[16 * LDY])smem;

  int w = tid >> 6;
  int lane = tid & 63;
  int lrow = lane & 15;
  int lch = lane >> 4;
  int r0w = blockIdx.x * 64 + w * 16;
  bool active = (r0w < M);

  for (int idx = tid; idx < NOUT * K; idx += 256) {
    int k = idx / NOUT, c = idx - k * NOUT;
    wts[c * LDW + k] = __float2half(Wg[idx]);
  }
  __syncthreads();

  f32x4 acc[NT];
#pragma unroll
  for (int nt = 0; nt < NT; nt++) acc[nt] = (f32x4){0.f, 0.f, 0.f, 0.f};

  if (active) {
    half8 afrag[KK];
    if constexpr (sizeof(AT) == 4) {
      const float* arow = (const float*)A + (size_t)(r0w + lrow) * K + lch * 8;
#pragma unroll
      for (int kk = 0; kk < KK; kk++) {
        float4 v0 = *(const float4*)(arow + kk * 32);
        float4 v1 = *(const float4*)(arow + kk * 32 + 4);
        half8 a;
        a[0] = (_Float16)v0.x; a[1] = (_Float16)v0.y;
        a[2] = (_Float16)v0.z; a[3] = (_Float16)v0.w;
        a[4] = (_Float16)v1.x; a[5] = (_Float16)v1.y;
        a[6] = (_Float16)v1.z; a[7] = (_Float16)v1.w;
        afrag[kk] = a;
      }
    } else {
      const __half* arow = (const __half*)A + (size_t)(r0w + lrow) * K + lch * 8;
#pragma unroll
      for (int kk = 0; kk < KK; kk++) afrag[kk] = *(const half8*)(arow + kk * 32);
    }

#pragma unroll
    for (int kk = 0; kk < KK; kk++) {
#pragma unroll
      for (int nt = 0; nt < NT; nt++) {
        half8 b = *(const half8*)&wts[(nt * 16 + lrow) * LDW + kk * 32 + lch * 8];
        acc[nt] = __builtin_amdgcn_mfma_f32_16x16x32_f16(afrag[kk], b, acc[nt], 0, 0, 0);
      }
    }

    float asw[NT], adw[NT];
#pragma unroll
    for (int nt = 0; nt < NT; nt++) {
      asw[nt] = att_s[nt * 16 + lrow];
      adw[nt] = att_d[nt * 16 + lrow];
    }
#pragma unroll
    for (int h = 0; h < H; h++) {
#pragma unroll
      for (int reg = 0; reg < 4; reg++) {
        float ps = 0.f, pd = 0.f;
#pragma unroll
        for (int nt = h * NTH; nt < (h + 1) * NTH; nt++) {
          ps = fmaf(acc[nt][reg], asw[nt], ps);
          pd = fmaf(acc[nt][reg], adw[nt], pd);
        }
#pragma unroll
        for (int o = 1; o < 16; o <<= 1) {
          ps += __shfl_xor(ps, o);
          pd += __shfl_xor(pd, o);
        }
        if (lrow == 0) {
          int row = r0w + lch * 4 + reg;
          AS[row * H + h] = ps;
          AD[row * H + h] = pd;
        }
      }
    }
  }

  __syncthreads();  // wts dead; ylds may overwrite

  if (active) {
#pragma unroll
    for (int nt = 0; nt < NT; nt++) {
#pragma unroll
      for (int reg = 0; reg < 4; reg++) {
        ylds[w][(lch * 4 + reg) * LDY + nt * 16 + lrow] = __float2half(acc[nt][reg]);
      }
    }
  }
  __syncthreads();

  if (active) {
    constexpr int YCH = NOUT / 8;
    for (int idx = lane; idx < 16 * YCH; idx += 64) {
      int row = idx / YCH, ch = idx % YCH;
      uint4 v = *(const uint4*)&ylds[w][row * LDY + ch * 8];
      *(uint4*)(Y + (size_t)(r0w + row) * NOUT + ch * 8) = v;
    }
  }
}

// ---------------- build: bucket slabs -> exact CSR ----------------

template <int CAP>  // 12288
__global__ void build_kernel(const unsigned int* __restrict__ binned,
                             const int* __restrict__ cursor, int* __restrict__ offsets,
                             int* __restrict__ csr_src, int Nn, int Etot, int nbk, int capb) {
  __shared__ int nhist[256];
  __shared__ int lcur[256];
  __shared__ int shws[8];
  __shared__ int sbase, ssz;
  __shared__ unsigned short stage[CAP];
  int b = blockIdx.x;
  int t = threadIdx.x;

  int gv = (t < nbk) ? cursor[t] : 0;
  int incl = scan256(gv, shws);
  if (t == b) { sbase = incl - gv; ssz = gv; }
  __syncthreads();
  int csrbase = sbase;
  int sz = ssz;
  int binbase = b * capb;

  nhist[t] = 0;
  __syncthreads();
  for (int i = t; i < sz; i += 256) atomicAdd(&nhist[binned[binbase + i] & 255], 1);
  __syncthreads();

  int hv = nhist[t];
  int incl2 = scan256(hv, shws);
  int excl = incl2 - hv;
  int node = (b << 8) + t;
  if (node < Nn) offsets[node] = csrbase + excl;
  if (b == nbk - 1 && t == 0) offsets[Nn] = Etot;
  lcur[t] = excl;
  __syncthreads();

  if (sz <= CAP) {
    for (int i = t; i < sz; i += 256) {
      unsigned int v = binned[binbase + i];
      int lp = atomicAdd(&lcur[v & 255], 1);
      stage[lp] = (unsigned short)((v >> 8) & 0xFFFFu);
    }
    __syncthreads();
    for (int i = t; i < sz; i += 256) csr_src[csrbase + i] = (int)stage[i];
  } else {
    for (int i = t; i < sz; i += 256) {
      unsigned int v = binned[binbase + i];
      int lp = atomicAdd(&lcur[v & 255], 1);
      csr_src[csrbase + lp] = (int)((v >> 8) & 0xFFFFu);
    }
  }
}

// ---------------- node softmax + aggregate ----------------

static __device__ __forceinline__ void fma8(uint4 u, float e, float* __restrict__ acc) {
  float2 f0 = __half22float2(*(const __half2*)&u.x);
  float2 f1 = __half22float2(*(((const __half2*)&u.x) + 1));
  float2 f2 = __half22float2(*(const __half2*)&u.z);
  float2 f3 = __half22float2(*(((const __half2*)&u.z) + 1));
  acc[0] = fmaf(e, f0.x, acc[0]); acc[1] = fmaf(e, f0.y, acc[1]);
  acc[2] = fmaf(e, f1.x, acc[2]); acc[3] = fmaf(e, f1.y, acc[3]);
  acc[4] = fmaf(e, f2.x, acc[4]); acc[5] = fmaf(e, f2.y, acc[5]);
  acc[6] = fmaf(e, f3.x, acc[6]); acc[7] = fmaf(e, f3.y, acc[7]);
}

static __device__ __forceinline__ void pk4(uint4 u, unsigned ep, __half2* __restrict__ acc2) {
  __half2 e2 = *(const __half2*)&ep;
  acc2[0] = __hfma2(e2, *(const __half2*)&u.x, acc2[0]);
  acc2[1] = __hfma2(e2, *(((const __half2*)&u.x) + 1), acc2[1]);
  acc2[2] = __hfma2(e2, *(const __half2*)&u.z, acc2[2]);
  acc2[3] = __hfma2(e2, *(((const __half2*)&u.z) + 1), acc2[3]);
}

// One wave per node (XCD-swizzled). H=2: 16 lanes/edge; H=1: 8 lanes/edge.
template <int H, bool RELU, typename OT>
__global__ void node_kernel(const int* __restrict__ offsets, const int* __restrict__ csr_src,
                            const float* __restrict__ AS, const float* __restrict__ AD,
                            const __half* __restrict__ XPH, const float* __restrict__ bias,
                            OT* __restrict__ OUT, int Nn) {
  constexpr int ROWH = H * 64;
  constexpr int LPE = (H == 2) ? 16 : 8;
  constexpr int G = 64 / LPE;
  int n = xcd_swz(blockIdx.x, Nn);
  int lane = threadIdx.x & 63;
  int g = lane / LPE;
  int sub = lane & (LPE - 1);

  int beg = offsets[n], end = offsets[n + 1];
  int deg = end - beg;

  const __half* base = XPH + sub * 8;

  float acc[8];
#pragma unroll
  for (int k = 0; k < 8; k++) acc[k] = 0.f;
  float z0 = 0.f, z1 = 0.f;

  float ad0, ad1 = 0.f;
  if constexpr (H == 2) {
    float2 adn = ((const float2*)AD)[n];
    ad0 = adn.x; ad1 = adn.y;
  } else {
    ad0 = AD[n];
  }

  if constexpr (H == 2) {
    float2 asn = ((const float2*)AS)[n];
    float es0 = __expf(lrelu(asn.x + ad0));
    float es1 = __expf(lrelu(asn.y + ad1));
    if (g == 0) {
      uint4 u = *(const uint4*)(base + (size_t)n * ROWH);
      fma8(u, (lane & 8) ? es1 : es0, acc);
    }
    if (lane == 0) { z0 = es0; z1 = es1; }
  } else {
    float es = __expf(lrelu(AS[n] + ad0));
    if (g == 0) {
      uint4 u = *(const uint4*)(base + (size_t)n * ROWH);
      fma8(u, es, acc);
    }
    if (lane == 0) z0 = es;
  }

  for (int i0 = 0; i0 < deg; i0 += 64) {
    int cnt = min(64, deg - i0);
    int srcv = 0;
    int epk = 0;
    float ev0 = 0.f, ev1 = 0.f;
    if (lane < cnt) {
      srcv = csr_src[beg + i0 + lane];
      if constexpr (H == 2) {
        float2 asv = ((const float2*)AS)[srcv];
        ev0 = __expf(lrelu(asv.x + ad0));
        ev1 = __expf(lrelu(asv.y + ad1));
        __half h0 = __float2half(ev0), h1 = __float2half(ev1);
        epk = (int)(((unsigned)*(unsigned short*)&h1 << 16) | *(unsigned short*)&h0);
      } else {
        ev0 = __expf(lrelu(AS[srcv] + ad0));
        __half h0 = __float2half(ev0);
        unsigned short us = *(unsigned short*)&h0;
        epk = (int)(((unsigned)us << 16) | us);
      }
    }
    z0 += ev0;
    if constexpr (H == 2) z1 += ev1;

    auto sel = [&](int p) -> unsigned {
      unsigned short us;
      if constexpr (H == 2)
        us = (lane & 8) ? (unsigned short)((unsigned)p >> 16) : (unsigned short)((unsigned)p & 0xFFFFu);
      else
        us = (unsigned short)((unsigned)p & 0xFFFFu);
      return ((unsigned)us << 16) | us;
    };

    int j = 0;
    for (; j + 4 * G <= cnt; j += 4 * G) {
      int s0 = __shfl(srcv, j + g),         s1 = __shfl(srcv, j + G + g);
      int s2 = __shfl(srcv, j + 2 * G + g), s3 = __shfl(srcv, j + 3 * G + g);
      int p0 = __shfl(epk, j + g),          p1 = __shfl(epk, j + G + g);
      int p2 = __shfl(epk, j + 2 * G + g),  p3 = __shfl(epk, j + 3 * G + g);
      uint4 u0 = *(const uint4*)(base + (size_t)s0 * ROWH);
      uint4 u1 = *(const uint4*)(base + (size_t)s1 * ROWH);
      uint4 u2 = *(const uint4*)(base + (size_t)s2 * ROWH);
      uint4 u3 = *(const uint4*)(base + (size_t)s3 * ROWH);
      __half2 acc2[4];
      acc2[0] = __half2(__half(0.f), __half(0.f));
      acc2[1] = acc2[0]; acc2[2] = acc2[0]; acc2[3] = acc2[0];
      pk4(u0, sel(p0), acc2);
      pk4(u1, sel(p1), acc2);
      pk4(u2, sel(p2), acc2);
      pk4(u3, sel(p3), acc2);
#pragma unroll
      for (int k = 0; k < 4; k++) {
        float2 f = __half22float2(acc2[k]);
        acc[2 * k] += f.x;
        acc[2 * k + 1] += f.y;
      }
    }
    for (; j + G <= cnt; j += G) {
      int s = __shfl(srcv, j + g);
      int p = __shfl(epk, j + g);
      __half_raw hr; hr.x = (unsigned short)(sel(p) & 0xFFFFu);
      float e = __half2float(__half(hr));
      uint4 u = *(const uint4*)(base + (size_t)s * ROWH);
      fma8(u, e, acc);
    }
    if (j < cnt) {
      int idx = j + g;
      int s = __shfl(srcv, idx & 63);
      int p = __shfl(epk, idx & 63);
      if (idx < cnt) {
        __half_raw hr; hr.x = (unsigned short)(sel(p) & 0xFFFFu);
        float e = __half2float(__half(hr));
        uint4 u = *(const uint4*)(base + (size_t)s * ROWH);
        fma8(u, e, acc);
      }
    }
  }

#pragma unroll
  for (int o = LPE; o <= 32; o <<= 1) {
#pragma unroll
    for (int k = 0; k < 8; k++) acc[k] += __shfl_xor(acc[k], o);
  }
  for (int o = 32; o > 0; o >>= 1) {
    z0 += __shfl_xor(z0, o);
    if constexpr (H == 2) z1 += __shfl_xor(z1, o);
  }
  float inv;
  if constexpr (H == 2) inv = 1.0f / ((lane & 8) ? z1 : z0);
  else inv = 1.0f / z0;

  if (g == 0) {
    const float* bp = bias + sub * 8;
    float r[8];
#pragma unroll
    for (int k = 0; k < 8; k++) {
      r[k] = fmaf(acc[k], inv, bp[k]);
      if (RELU) r[k] = fmaxf(r[k], 0.f);
    }
    if constexpr (sizeof(OT) == 4) {
      float* op = (float*)OUT + (size_t)n * ROWH + sub * 8;
      ((float4*)op)[0] = make_float4(r[0], r[1], r[2], r[3]);
      ((float4*)op)[1] = make_float4(r[4], r[5], r[6], r[7]);
    } else {
      __half* op = (__half*)OUT + (size_t)n * ROWH + sub * 8;
      __half2 h0 = __floats2half2_rn(r[0], r[1]);
      __half2 h1 = __floats2half2_rn(r[2], r[3]);
      __half2 h2 = __floats2half2_rn(r[4], r[5]);
      __half2 h3 = __floats2half2_rn(r[6], r[7]);
      uint4 u;
      u.x = *(unsigned int*)&h0; u.y = *(unsigned int*)&h1;
      u.z = *(unsigned int*)&h2; u.w = *(unsigned int*)&h3;
      *(uint4*)op = u;
    }
  }
}

// ---------------- launch ----------------

static inline size_t alignup(size_t x) { return (x + 255) & ~(size_t)255; }

extern "C" void kernel_launch(void* const* d_in, const int* in_sizes, int n_in,
                              void* d_out, int out_size, void* d_ws, size_t ws_size,
                              hipStream_t stream) {
  const float* x    = (const float*)d_in[0];
  const int*   edges= (const int*)d_in[1];
  const float* W1   = (const float*)d_in[2];
  const float* as1w = (const float*)d_in[3];
  const float* ad1w = (const float*)d_in[4];
  const float* b1   = (const float*)d_in[5];
  const float* W2   = (const float*)d_in[6];
  const float* as2w = (const float*)d_in[7];
  const float* ad2w = (const float*)d_in[8];
  const float* b2   = (const float*)d_in[9];

  const int N = in_sizes[0] / 128;   // 50000
  const int E = in_sizes[1] / 2;     // 1600000
  const int* src = edges;
  const int* dst = edges + E;
  const int nbk = (N + 255) >> 8;    // 196 buckets

  constexpr int CHUNK = 4096;
  constexpr int CAPB = 10240;        // slab capacity per bucket

  char* p = (char*)d_ws;
  size_t off = 0;
  auto take = [&](size_t bytes) { char* r = p + off; off = alignup(off + bytes); return r; };
  __half* xph1 = (__half*)take((size_t)N * 128 * 2);  // row-major [N][128]
  __half* xph2 = (__half*)take((size_t)N * 64 * 2);
  __half* hbuf = (__half*)take((size_t)N * 128 * 2);
  float* as1   = (float*)take((size_t)N * 2 * 4);
  float* ad1   = (float*)take((size_t)N * 2 * 4);
  float* as2   = (float*)take((size_t)N * 4);
  float* ad2   = (float*)take((size_t)N * 4);
  int* offsets = (int*)take((size_t)(N + 1) * 4);
  int* csr_src = (int*)take((size_t)E * 4);
  unsigned int* binned = (unsigned int*)take((size_t)nbk * CAPB * 4);
  int* cursor  = (int*)take((size_t)NBK_MAX * 4);
  (void)ws_size;

  const int binBlocks = (E + CHUNK - 1) / CHUNK;   // 391
  const int gemmBlocks = (N + 63) / 64;            // 782

  hipMemsetAsync(cursor, 0, (size_t)NBK_MAX * 4, stream);

  // MEGA: gemm1 blocks [0,gemmBlocks) + bin blocks [gemmBlocks, +binBlocks)
  gemm_bin_mfma<128, 128, 2, true, CHUNK, float><<<gemmBlocks + binBlocks, 256, 0, stream>>>(
      x, W1, as1w, ad1w, xph1, as1, ad1, N, gemmBlocks,
      src, dst, cursor, binned, E, nbk, CAPB);

  build_kernel<12288><<<nbk, 256, 0, stream>>>(binned, cursor, offsets, csr_src, N, E, nbk, CAPB);

  // layer 1 node aggregation (merged heads, XCD-swizzled)
  node_kernel<2, true, __half><<<N, 64, 0, stream>>>(
      offsets, csr_src, as1, ad1, xph1, b1, hbuf, N);

  // layer 2
  gemm_bin_mfma<128, 64, 1, false, CHUNK, __half><<<gemmBlocks, 256, 0, stream>>>(
      hbuf, W2, as2w, ad2w, xph2, as2, ad2, N, gemmBlocks,
      nullptr, nullptr, nullptr, nullptr, 0, nbk, CAPB);
  node_kernel<1, false, float><<<N, 64, 0, stream>>>(
      offsets, csr_src, as2, ad2, xph2, b2, (float*)d_out, N);
}